// Round 4
// baseline (744.370 us; speedup 1.0000x reference)
//
#include <hip/hip_runtime.h>
#include <hip/hip_bf16.h>
#include <cstdint>
#include <cstddef>

// Problem constants
#define E_   8
#define H_   2048
#define I_   2816
#define T_   512
#define NPAIR 1024         // T*K (token,k) pairs

// GEMM tiling: 8-wave blocks for 2x TLP vs the 4-wave rounds 1/3.
#define TM   256           // one m-tile per expert (cnt ~ 128 +- 11) -> weights streamed once
#define TN   32
#define BK   64
#define MT_  2             // m-frags per wave (256 / 8 waves / 16)

typedef __attribute__((ext_vector_type(8))) short          bf16x8;
typedef __attribute__((ext_vector_type(4))) float          f32x4;
typedef __attribute__((ext_vector_type(8))) unsigned short u16x8;

__device__ __forceinline__ unsigned short f2bf(float f){
  union { float f; unsigned u; } a; a.f = f;
  unsigned u = a.u;
  unsigned r = u + 0x7fffu + ((u >> 16) & 1u);   // RNE
  return (unsigned short)(r >> 16);
}

__device__ __forceinline__ void cvt4(u16x8& dst, int base, const float4 v, float s){
  __hip_bfloat162 p0 = __float22bfloat162_rn(float2{v.x*s, v.y*s});
  __hip_bfloat162 p1 = __float22bfloat162_rn(float2{v.z*s, v.w*s});
  union { __hip_bfloat162 b; unsigned u; } a0{p0}, a1{p1};
  dst[base+0] = (unsigned short)(a0.u & 0xffff);
  dst[base+1] = (unsigned short)(a0.u >> 16);
  dst[base+2] = (unsigned short)(a1.u & 0xffff);
  dst[base+3] = (unsigned short)(a1.u >> 16);
}

__device__ __forceinline__ bf16x8 u2b(u16x8 v){
  union { u16x8 u; bf16x8 b; } x; x.u = v; return x.b;
}

// async global->LDS, 16B per lane. LDS dest = wave-uniform base + lane*16.
__device__ __forceinline__ void gload_lds16(const void* g, void* l){
  __builtin_amdgcn_global_load_lds(
      (const __attribute__((address_space(1))) unsigned int*)g,
      (__attribute__((address_space(3))) unsigned int*)l, 16, 0, 0);
}

// ---------------------------------------------------------------------------
// Routing: bucket 1024 (t,k) pairs by expert; also inverse map slot-of-pair.
// ---------------------------------------------------------------------------
__global__ void route_kernel(const int* __restrict__ ids,
                             int* __restrict__ offs, int* __restrict__ ptok,
                             int* __restrict__ sop){
  __shared__ int scnt[E_];
  __shared__ int scur[E_];
  const int tid = threadIdx.x;
  if (tid < E_) scnt[tid] = 0;
  __syncthreads();
  const int e = ids[tid];
  atomicAdd(&scnt[e], 1);
  __syncthreads();
  if (tid == 0){
    int s = 0;
    for (int i = 0; i < E_; i++){ offs[i] = s; scur[i] = s; s += scnt[i]; }
    offs[E_] = s;
  }
  __syncthreads();
  const int pos = atomicAdd(&scur[e], 1);
  ptok[pos] = tid >> 1;
  sop[tid]  = pos;
}

// ---------------------------------------------------------------------------
// Prep: gather+convert x rows into slot order, bf16. xg[slot][H]
// ---------------------------------------------------------------------------
__global__ void prep_kernel(const float* __restrict__ x, const int* __restrict__ ptok,
                            unsigned short* __restrict__ xg){
  const int slot = blockIdx.x;
  const int tok  = ptok[slot];
  const int k0   = threadIdx.x * 8;
  const float4 v0 = *(const float4*)(x + (size_t)tok*H_ + k0);
  const float4 v1 = *(const float4*)(x + (size_t)tok*H_ + k0 + 4);
  u16x8 o;
  cvt4(o, 0, v0, 1.f);
  cvt4(o, 4, v1, 1.f);
  *(u16x8*)(xg + (size_t)slot*H_ + k0) = o;
}

// ---------------------------------------------------------------------------
// GEMM1: act[slot,i] = silu(x@Wg^T)*(x@Wu^T).
// 8-wave (512-thread) blocks, TM=256: doubles waves/SIMD vs the 4-wave
// variants (rounds 1/3 both latency-stalled at ~2.75 waves/SIMD).
// B path: f32 tiles DMA'd global->LDS (global_load_lds) into a 3-deep ring,
// counted vmcnt waits (never drain in steady state). Dequant at LDS->reg
// read. Bank conflicts: both-sides XOR swizzle (16B granule, (row&7)<<4).
// XCD pinning: blockIdx.x == expert, gridDim.x == 8 == #XCDs.
// grid: (E=8, I/TN=88, 4), block 512.
// ---------------------------------------------------------------------------
__global__ __launch_bounds__(512, 4)
void gemm1_kernel(const unsigned short* __restrict__ xg, const float* __restrict__ w13,
                  const float* __restrict__ s13, const int* __restrict__ offs,
                  unsigned short* __restrict__ act)
{
  const int e   = blockIdx.x;
  const int off = offs[e];
  const int cnt = offs[e+1] - off;
  const int m0  = blockIdx.z * TM;
  if (m0 >= cnt) return;
  const int rows = min(TM, cnt - m0);
  const int nb   = blockIdx.y * TN;

  __shared__ __align__(16) float Bs[3][2*TN][BK];   // 3 x 16KB ring

  const int tid  = threadIdx.x;
  const int wv   = tid >> 6;          // 0..7
  const int lane = tid & 63;
  const int quad = lane >> 4;
  const int l16  = lane & 15;

  const float* w13e = w13 + (size_t)e * (2*I_) * H_;
  const float* s13e = s13 + (size_t)e * (2*I_/128) * (H_/128);

  // scale rows (uniform across block: 32 | 128)
  const int s0row = (nb >> 7) * (H_/128);
  const int s1row = ((I_/128) + (nb >> 7)) * (H_/128);

  // Staging: wave wv stages LDS rows [wv*8, wv*8+8): 2 insts x 4 rows.
  // Pre-swizzled global source: col byte = ((lane&15)*16) ^ ((row&7)*16).
  const char* srcP[2];
  #pragma unroll
  for (int j = 0; j < 2; j++){
    const int rl = wv*8 + j*4 + (lane >> 4);
    const int gr = (rl < TN) ? (nb + rl) : (I_ + nb + (rl - TN));
    const int cb = ((lane & 15) << 4) ^ ((rl & 7) << 4);
    srcP[j] = (const char*)(w13e + (size_t)gr * H_) + cb;
  }
  auto stage = [&](int t, int slot){
    #pragma unroll
    for (int j = 0; j < 2; j++)
      gload_lds16(srcP[j] + (size_t)t * (BK*4), &Bs[slot][wv*8 + j*4][0]);
  };

  // A fragment row pointers (clamped; OOB rows discarded in epilogue)
  const unsigned short* aP[MT_];
  #pragma unroll
  for (int mt = 0; mt < MT_; mt++){
    int sl = off + m0 + wv*(TM/8) + mt*16 + l16;
    sl = min(sl, NPAIR - 1);
    aP[mt] = xg + (size_t)sl * H_ + quad*8;
  }

  f32x4 acc[2][MT_][2];
  #pragma unroll
  for (int h = 0; h < 2; h++)
    #pragma unroll
    for (int mt = 0; mt < MT_; mt++)
      #pragma unroll
      for (int nt = 0; nt < 2; nt++)
        acc[h][mt][nt] = (f32x4){0.f, 0.f, 0.f, 0.f};

  bf16x8 A0[2][MT_], A1[2][MT_];
  auto loadA = [&](int t, bf16x8 (*A)[MT_]){
    #pragma unroll
    for (int kk = 0; kk < 2; kk++)
      #pragma unroll
      for (int mt = 0; mt < MT_; mt++)
        A[kk][mt] = *(const bf16x8*)(aP[mt] + t*BK + kk*32);
  };

  auto comp = [&](int slot, bf16x8 (*A)[MT_], float sg, float su){
    #pragma unroll
    for (int kk = 0; kk < 2; kk++)
      #pragma unroll
      for (int hh = 0; hh < 2; hh++){
        const float s = hh ? su : sg;
        #pragma unroll
        for (int nt = 0; nt < 2; nt++){
          const int row = hh*TN + nt*16 + l16;
          const int xr  = (row & 7) << 2;            // float units (=16B)
          const int cb  = kk*32 + quad*8;
          const float4 F0 = *(const float4*)&Bs[slot][row][cb ^ xr];
          const float4 F1 = *(const float4*)&Bs[slot][row][(cb + 4) ^ xr];
          u16x8 o; cvt4(o, 0, F0, s); cvt4(o, 4, F1, s);
          const bf16x8 bv = u2b(o);
          #pragma unroll
          for (int mt = 0; mt < MT_; mt++)
            acc[hh][mt][nt] = __builtin_amdgcn_mfma_f32_16x16x32_bf16(A[kk][mt], bv, acc[hh][mt][nt], 0, 0, 0);
        }
      }
  };

  const int NITER = H_/BK;   // 32
  // prologue
  loadA(0, A0);                                       // 4 loads
  stage(0, 0);                                        // 2
  stage(1, 1);                                        // 2
  asm volatile("s_waitcnt vmcnt(2)" ::: "memory");    // A(0)+stage(0) done; stage(1) in flight
  __builtin_amdgcn_s_barrier();
  loadA(1, A1);
  stage(2, 2);
  comp(0, A0, s13e[s0row], s13e[s1row]);

  for (int t = 1; t < NITER-1; t++){
    // drain own stage(t); keep loadA(t)[4] + stage(t+1)[2] in flight
    asm volatile("s_waitcnt vmcnt(6)" ::: "memory");
    __builtin_amdgcn_s_barrier();
    loadA(t+1, ((t+1) & 1) ? A1 : A0);
    if (t+2 < NITER) stage(t+2, (t+2) % 3);
    const float sg = s13e[s0row + (t >> 1)];
    const float su = s13e[s1row + (t >> 1)];
    comp(t % 3, (t & 1) ? A1 : A0, sg, su);
  }
  {  // final tile: outstanding = stage(last)[2] + loadA(last)[4]
    asm volatile("s_waitcnt vmcnt(4)" ::: "memory");
    __builtin_amdgcn_s_barrier();
    const int t = NITER-1;
    comp(t % 3, (t & 1) ? A1 : A0, s13e[s0row + (t >> 1)], s13e[s1row + (t >> 1)]);
  }

  // epilogue: act = silu(gate)*up
  #pragma unroll
  for (int mt = 0; mt < MT_; mt++){
    #pragma unroll
    for (int nt = 0; nt < 2; nt++){
      #pragma unroll
      for (int r = 0; r < 4; r++){
        const int m = wv*(TM/8) + mt*16 + quad*4 + r;
        if (m < rows){
          const float g = acc[0][mt][nt][r];
          const float u = acc[1][mt][nt][r];
          const float sg2 = g / (1.f + __expf(-g));
          act[(size_t)(off + m0 + m)*I_ + (nb + nt*16 + l16)] = f2bf(sg2 * u);
        }
      }
    }
  }
}

// ---------------------------------------------------------------------------
// GEMM2: buf[slot,h] = act @ W2^T. Same 8-wave ring pipeline; tile 32 rows.
// grid: (E=8, H/TN=64, 4), block 512.
// ---------------------------------------------------------------------------
__global__ __launch_bounds__(512, 4)
void gemm2_kernel(const unsigned short* __restrict__ act, const float* __restrict__ w2,
                  const float* __restrict__ s2, const int* __restrict__ offs,
                  float* __restrict__ buf)
{
  const int e   = blockIdx.x;
  const int off = offs[e];
  const int cnt = offs[e+1] - off;
  const int m0  = blockIdx.z * TM;
  if (m0 >= cnt) return;
  const int rows = min(TM, cnt - m0);
  const int nb   = blockIdx.y * TN;

  __shared__ __align__(16) float Bs[3][TN][BK];   // 3 x 8KB ring

  const int tid  = threadIdx.x;
  const int wv   = tid >> 6;
  const int lane = tid & 63;
  const int quad = lane >> 4;
  const int l16  = lane & 15;

  const float* w2e = w2 + (size_t)e * H_ * I_;
  const float* s2e = s2 + (size_t)e * (H_/128) * (I_/128);
  const int srow  = (nb >> 7) * (I_/128);

  // Staging: wave wv stages rows [wv*4, wv*4+4): 1 inst x 4 rows.
  const int rl = wv*4 + (lane >> 4);
  const int cb0 = ((lane & 15) << 4) ^ ((rl & 7) << 4);
  const char* srcP = (const char*)(w2e + (size_t)(nb + rl) * I_) + cb0;
  auto stage = [&](int t, int slot){
    gload_lds16(srcP + (size_t)t * (BK*4), &Bs[slot][wv*4][0]);
  };

  const unsigned short* aP[MT_];
  #pragma unroll
  for (int mt = 0; mt < MT_; mt++){
    int sl = off + m0 + wv*(TM/8) + mt*16 + l16;
    sl = min(sl, NPAIR - 1);
    aP[mt] = act + (size_t)sl * I_ + quad*8;
  }

  f32x4 acc[MT_][2];
  #pragma unroll
  for (int mt = 0; mt < MT_; mt++)
    #pragma unroll
    for (int nt = 0; nt < 2; nt++)
      acc[mt][nt] = (f32x4){0.f, 0.f, 0.f, 0.f};

  bf16x8 A0[2][MT_], A1[2][MT_];
  auto loadA = [&](int t, bf16x8 (*A)[MT_]){
    #pragma unroll
    for (int kk = 0; kk < 2; kk++)
      #pragma unroll
      for (int mt = 0; mt < MT_; mt++)
        A[kk][mt] = *(const bf16x8*)(aP[mt] + t*BK + kk*32);
  };

  auto comp = [&](int slot, bf16x8 (*A)[MT_], float s){
    #pragma unroll
    for (int kk = 0; kk < 2; kk++)
      #pragma unroll
      for (int nt = 0; nt < 2; nt++){
        const int row = nt*16 + l16;
        const int xr  = (row & 7) << 2;
        const int cb  = kk*32 + quad*8;
        const float4 F0 = *(const float4*)&Bs[slot][row][cb ^ xr];
        const float4 F1 = *(const float4*)&Bs[slot][row][(cb + 4) ^ xr];
        u16x8 o; cvt4(o, 0, F0, s); cvt4(o, 4, F1, s);
        const bf16x8 bv = u2b(o);
        #pragma unroll
        for (int mt = 0; mt < MT_; mt++)
          acc[mt][nt] = __builtin_amdgcn_mfma_f32_16x16x32_bf16(A[kk][mt], bv, acc[mt][nt], 0, 0, 0);
      }
  };

  const int NITER = I_/BK;   // 44
  loadA(0, A0);                                       // 4
  stage(0, 0);                                        // 1
  stage(1, 1);                                        // 1
  asm volatile("s_waitcnt vmcnt(1)" ::: "memory");    // A(0)+stage(0) done; stage(1) in flight
  __builtin_amdgcn_s_barrier();
  loadA(1, A1);
  stage(2, 2);
  comp(0, A0, s2e[srow]);

  for (int t = 1; t < NITER-1; t++){
    // drain own stage(t); keep loadA(t)[4] + stage(t+1)[1] in flight
    asm volatile("s_waitcnt vmcnt(5)" ::: "memory");
    __builtin_amdgcn_s_barrier();
    loadA(t+1, ((t+1) & 1) ? A1 : A0);
    if (t+2 < NITER) stage(t+2, (t+2) % 3);
    comp(t % 3, (t & 1) ? A1 : A0, s2e[srow + (t >> 1)]);
  }
  {
    asm volatile("s_waitcnt vmcnt(4)" ::: "memory");
    __builtin_amdgcn_s_barrier();
    const int t = NITER-1;
    comp(t % 3, (t & 1) ? A1 : A0, s2e[srow + (t >> 1)]);
  }

  // epilogue: plain stores per slot row
  #pragma unroll
  for (int mt = 0; mt < MT_; mt++){
    #pragma unroll
    for (int nt = 0; nt < 2; nt++){
      #pragma unroll
      for (int r = 0; r < 4; r++){
        const int m = wv*(TM/8) + mt*16 + quad*4 + r;
        if (m < rows)
          buf[(size_t)(off + m0 + m)*H_ + (nb + nt*16 + l16)] = acc[mt][nt][r];
      }
    }
  }
}

// ---------------------------------------------------------------------------
// Combine: out[t,:] = tw[2t]*buf[sop[2t],:] + tw[2t+1]*buf[sop[2t+1],:]
// ---------------------------------------------------------------------------
__global__ void combine_kernel(const float* __restrict__ buf, const int* __restrict__ sop,
                               const float* __restrict__ tw, float* __restrict__ out){
  const int gid = blockIdx.x*256 + threadIdx.x;
  const int t = gid >> 9;
  const int c = gid & 511;
  const int s0 = sop[2*t], s1 = sop[2*t+1];
  const float w0 = tw[2*t], w1 = tw[2*t+1];
  const float4 v0 = ((const float4*)buf)[(size_t)s0*(H_/4) + c];
  const float4 v1 = ((const float4*)buf)[(size_t)s1*(H_/4) + c];
  float4 o;
  o.x = w0*v0.x + w1*v1.x;
  o.y = w0*v0.y + w1*v1.y;
  o.z = w0*v0.z + w1*v1.z;
  o.w = w0*v0.w + w1*v1.w;
  ((float4*)out)[gid] = o;
}

// ---------------------------------------------------------------------------
extern "C" void kernel_launch(void* const* d_in, const int* in_sizes, int n_in,
                              void* d_out, int out_size, void* d_ws, size_t ws_size,
                              hipStream_t stream){
  const float* x   = (const float*)d_in[0];
  const int*   ids = (const int*)  d_in[1];
  const float* tw  = (const float*)d_in[2];
  const float* w13 = (const float*)d_in[3];
  const float* s13 = (const float*)d_in[4];
  const float* w2  = (const float*)d_in[5];
  const float* s2  = (const float*)d_in[6];
  float* out = (float*)d_out;

  char* ws = (char*)d_ws;
  int* offs = (int*)ws;                                   // 9 ints
  int* ptok = (int*)(ws + 64);                            // 1024 ints
  int* sop  = (int*)(ws + 64 + 4096);                     // 1024 ints
  unsigned short* xg  = (unsigned short*)(ws + 16384);    // [1024][H] bf16 (aliased by buf)
  float*          buf = (float*)(ws + 16384);             // [1024][H] f32
  unsigned short* act = (unsigned short*)(ws + 16384 + (size_t)NPAIR*H_*4);  // [1024][I] bf16

  route_kernel  <<<1, NPAIR, 0, stream>>>(ids, offs, ptok, sop);
  prep_kernel   <<<NPAIR, 256, 0, stream>>>(x, ptok, xg);
  gemm1_kernel  <<<dim3(E_, I_/TN, (NPAIR + TM - 1)/TM), 512, 0, stream>>>(xg, w13, s13, offs, act);
  gemm2_kernel  <<<dim3(E_, H_/TN, (NPAIR + TM - 1)/TM), 512, 0, stream>>>(act, w2, s2, offs, buf);
  combine_kernel<<<(T_*H_/4)/256, 256, 0, stream>>>(buf, sop, tw, out);
}

// Round 5
// 702.114 us; speedup vs baseline: 1.0602x; 1.0602x over previous
//
#include <hip/hip_runtime.h>
#include <hip/hip_bf16.h>
#include <cstdint>
#include <cstddef>

// Problem constants
#define E_   8
#define H_   2048
#define I_   2816
#define T_   512
#define NPAIR 1024         // T*K (token,k) pairs

// GEMM tiling
#define TM   192           // one m-tile per expert w.h.p. -> weights streamed once
#define TN   32
#define BK   64
#define MT_  3             // m-frags per wave (192 / 4 waves / 16)

typedef __attribute__((ext_vector_type(8))) short          bf16x8;
typedef __attribute__((ext_vector_type(4))) float          f32x4;
typedef __attribute__((ext_vector_type(4))) int            i32x4;
typedef __attribute__((ext_vector_type(8))) unsigned short u16x8;

__device__ __forceinline__ unsigned short f2bf(float f){
  union { float f; unsigned u; } a; a.f = f;
  unsigned u = a.u;
  unsigned r = u + 0x7fffu + ((u >> 16) & 1u);   // RNE
  return (unsigned short)(r >> 16);
}

__device__ __forceinline__ void cvt4(u16x8& dst, int base, const float4 v, float s){
  __hip_bfloat162 p0 = __float22bfloat162_rn(float2{v.x*s, v.y*s});
  __hip_bfloat162 p1 = __float22bfloat162_rn(float2{v.z*s, v.w*s});
  union { __hip_bfloat162 b; unsigned u; } a0{p0}, a1{p1};
  dst[base+0] = (unsigned short)(a0.u & 0xffff);
  dst[base+1] = (unsigned short)(a0.u >> 16);
  dst[base+2] = (unsigned short)(a1.u & 0xffff);
  dst[base+3] = (unsigned short)(a1.u >> 16);
}

__device__ __forceinline__ bf16x8 u2b(u16x8 v){
  union { u16x8 u; bf16x8 b; } x; x.u = v; return x.b;
}

// async global->LDS, 16B per lane. No VGPR defined -> invisible to the
// compiler's waitcnt insertion; only OUR counted vmcnt waits govern it.
__device__ __forceinline__ void gload_lds16(const void* g, void* l){
  __builtin_amdgcn_global_load_lds(
      (const __attribute__((address_space(1))) unsigned int*)g,
      (__attribute__((address_space(3))) unsigned int*)l, 16, 0, 0);
}

// inline-asm 16B global load: the defined VGPRs are asm outputs, so the
// compiler does NOT insert s_waitcnt for their use -- our counted vmcnt
// waits (which by schedule cover these loads) are the only waits.
__device__ __forceinline__ i32x4 gload16(const void* p){
  i32x4 r;
  asm volatile("global_load_dwordx4 %0, %1, off" : "=v"(r) : "v"(p));
  return r;
}

// counted-vmcnt wave sync: drain to N, pin schedule (rule 18), then barrier.
#define WAIT_BAR(N)                                            \
  asm volatile("s_waitcnt vmcnt(" #N ")" ::: "memory");        \
  __builtin_amdgcn_sched_barrier(0);                           \
  __builtin_amdgcn_s_barrier();

// ---------------------------------------------------------------------------
// Routing: bucket 1024 (t,k) pairs by expert; also inverse map slot-of-pair.
// ---------------------------------------------------------------------------
__global__ void route_kernel(const int* __restrict__ ids,
                             int* __restrict__ offs, int* __restrict__ ptok,
                             int* __restrict__ sop){
  __shared__ int scnt[E_];
  __shared__ int scur[E_];
  const int tid = threadIdx.x;
  if (tid < E_) scnt[tid] = 0;
  __syncthreads();
  const int e = ids[tid];
  atomicAdd(&scnt[e], 1);
  __syncthreads();
  if (tid == 0){
    int s = 0;
    for (int i = 0; i < E_; i++){ offs[i] = s; scur[i] = s; s += scnt[i]; }
    offs[E_] = s;
  }
  __syncthreads();
  const int pos = atomicAdd(&scur[e], 1);
  ptok[pos] = tid >> 1;
  sop[tid]  = pos;
}

// ---------------------------------------------------------------------------
// Prep: gather+convert x rows into slot order, bf16. xg[slot][H]
// ---------------------------------------------------------------------------
__global__ void prep_kernel(const float* __restrict__ x, const int* __restrict__ ptok,
                            unsigned short* __restrict__ xg){
  const int slot = blockIdx.x;
  const int tok  = ptok[slot];
  const int k0   = threadIdx.x * 8;
  const float4 v0 = *(const float4*)(x + (size_t)tok*H_ + k0);
  const float4 v1 = *(const float4*)(x + (size_t)tok*H_ + k0 + 4);
  u16x8 o;
  cvt4(o, 0, v0, 1.f);
  cvt4(o, 4, v1, 1.f);
  *(u16x8*)(xg + (size_t)slot*H_ + k0) = o;
}

// ---------------------------------------------------------------------------
// GEMM1: act[slot,i] = silu(x@Wg^T)*(x@Wu^T).
// Fully DMA/asm K-loop: NO compiler-tracked VMEM->VGPR loads inside -> the
// counted vmcnt waits below are the ONLY waits; B-stage ring (4-deep, dist
// 2-3) and A-reg ring (4 named bufs, dist 2) stay in flight across barriers.
// Steady state: wait vmcnt(14) = drain{stage(t), loadA(t)}, keep
// {stage(t+1)[4], loadA(t+1)[6], stage(t+2)[4]}. Bank conflicts: both-sides
// XOR swizzle (16B granule, (row&7)<<4). XCD pinning: blockIdx.x == expert.
// grid: (E=8, I/TN=88, 6), block 256.
// ---------------------------------------------------------------------------
__global__ __launch_bounds__(256, 2)
void gemm1_kernel(const unsigned short* __restrict__ xg, const float* __restrict__ w13,
                  const float* __restrict__ s13, const int* __restrict__ offs,
                  unsigned short* __restrict__ act)
{
  const int e   = blockIdx.x;
  const int off = offs[e];
  const int cnt = offs[e+1] - off;
  const int m0  = blockIdx.z * TM;
  if (m0 >= cnt) return;
  const int rows = min(TM, cnt - m0);
  const int nb   = blockIdx.y * TN;

  __shared__ __align__(16) float Bs[4][2*TN][BK];   // 4 x 16KB ring = 64 KB

  const int tid  = threadIdx.x;
  const int wv   = tid >> 6;
  const int lane = tid & 63;
  const int quad = lane >> 4;
  const int l16  = lane & 15;

  const float* w13e = w13 + (size_t)e * (2*I_) * H_;
  const float* s13e = s13 + (size_t)e * (2*I_/128) * (H_/128);

  const int s0row = (nb >> 7) * (H_/128);
  const int s1row = ((I_/128) + (nb >> 7)) * (H_/128);

  // B staging: wave wv stages LDS rows [wv*16, wv*16+16): 4 insts x 4 rows.
  // Pre-swizzled global source col byte = ((lane&15)*16) ^ ((row&7)*16).
  const char* srcP[4];
  #pragma unroll
  for (int j = 0; j < 4; j++){
    const int rl = wv*16 + j*4 + (lane >> 4);
    const int gr = (rl < TN) ? (nb + rl) : (I_ + nb + (rl - TN));
    const int cb = ((lane & 15) << 4) ^ ((rl & 7) << 4);
    srcP[j] = (const char*)(w13e + (size_t)gr * H_) + cb;
  }
  auto stage = [&](int t, int slot){
    #pragma unroll
    for (int j = 0; j < 4; j++)
      gload_lds16(srcP[j] + (size_t)t * (BK*4), &Bs[slot][wv*16 + j*4][0]);
  };

  // A fragment row pointers (clamped; OOB rows discarded in epilogue)
  const unsigned short* aP[MT_];
  #pragma unroll
  for (int mt = 0; mt < MT_; mt++){
    int sl = off + m0 + wv*(TM/4) + mt*16 + l16;
    sl = min(sl, NPAIR - 1);
    aP[mt] = xg + (size_t)sl * H_ + quad*8;
  }

  f32x4 acc[2][MT_][2];
  #pragma unroll
  for (int h = 0; h < 2; h++)
    #pragma unroll
    for (int mt = 0; mt < MT_; mt++)
      #pragma unroll
      for (int nt = 0; nt < 2; nt++)
        acc[h][mt][nt] = (f32x4){0.f, 0.f, 0.f, 0.f};

  // A register ring: 4 named buffers (static indexing only), 6 x 16B each
  i32x4 A0[6], A1[6], A2[6], A3[6];
  auto loadA = [&](int t, i32x4* A){
    #pragma unroll
    for (int kk = 0; kk < 2; kk++)
      #pragma unroll
      for (int mt = 0; mt < MT_; mt++)
        A[kk*MT_ + mt] = gload16(aP[mt] + t*BK + kk*32);
  };

  auto comp = [&](int slot, const i32x4* A, float sg, float su){
    #pragma unroll
    for (int kk = 0; kk < 2; kk++)
      #pragma unroll
      for (int hh = 0; hh < 2; hh++){
        const float s = hh ? su : sg;
        #pragma unroll
        for (int nt = 0; nt < 2; nt++){
          const int row = hh*TN + nt*16 + l16;
          const int xr  = (row & 7) << 2;            // float units (=16B)
          const int cb  = kk*32 + quad*8;
          const float4 F0 = *(const float4*)&Bs[slot][row][cb ^ xr];
          const float4 F1 = *(const float4*)&Bs[slot][row][(cb + 4) ^ xr];
          u16x8 o; cvt4(o, 0, F0, s); cvt4(o, 4, F1, s);
          const bf16x8 bv = u2b(o);
          #pragma unroll
          for (int mt = 0; mt < MT_; mt++){
            const bf16x8 av = *(const bf16x8*)&A[kk*MT_ + mt];
            acc[hh][mt][nt] = __builtin_amdgcn_mfma_f32_16x16x32_bf16(av, bv, acc[hh][mt][nt], 0, 0, 0);
          }
        }
      }
  };

  const int NITER = H_/BK;   // 32
  // prologue. Issue order matters for the counted waits:
  // loadA(0)[6], stage(0)[4], stage(1)[4], loadA(1)[6], stage(2)[4] = 24 ops
  loadA(0, A0);
  stage(0, 0);
  stage(1, 1);
  loadA(1, A1);
  stage(2, 2);
  WAIT_BAR(14)                     // drain loadA(0)+stage(0)
  loadA(2, A2);
  stage(3, 3);
  comp(0, A0, s13e[s0row], s13e[s1row]);

#define G1_STEP(T, AL, AC)                                        \
  { WAIT_BAR(14)                                                  \
    loadA((T)+2, AL);                                             \
    stage((T)+3, ((T)+3) & 3);                                    \
    comp((T) & 3, AC, s13e[s0row + ((T) >> 1)], s13e[s1row + ((T) >> 1)]); }

  for (int tb = 1; tb <= 25; tb += 4){
    G1_STEP(tb+0, A3, A1)
    G1_STEP(tb+1, A0, A2)
    G1_STEP(tb+2, A1, A3)
    G1_STEP(tb+3, A2, A0)
  }
  // t = 29 (steady wait; loadA(31), no stage)
  { WAIT_BAR(14)
    loadA(31, A3);
    comp(1, A1, s13e[s0row + 14], s13e[s1row + 14]); }
  // t = 30: outstanding = stage(30)4, loadA(30)6, stage(31)4, loadA(31)6
  { WAIT_BAR(10)
    comp(2, A2, s13e[s0row + 15], s13e[s1row + 15]); }
  // t = 31
  { WAIT_BAR(0)
    comp(3, A3, s13e[s0row + 15], s13e[s1row + 15]); }
#undef G1_STEP

  // epilogue: act = silu(gate)*up
  #pragma unroll
  for (int mt = 0; mt < MT_; mt++){
    #pragma unroll
    for (int nt = 0; nt < 2; nt++){
      #pragma unroll
      for (int r = 0; r < 4; r++){
        const int m = wv*(TM/4) + mt*16 + quad*4 + r;
        if (m < rows){
          const float g = acc[0][mt][nt][r];
          const float u = acc[1][mt][nt][r];
          const float sg2 = g / (1.f + __expf(-g));
          act[(size_t)(off + m0 + m)*I_ + (nb + nt*16 + l16)] = f2bf(sg2 * u);
        }
      }
    }
  }
}

// ---------------------------------------------------------------------------
// GEMM2: buf[slot,h] = act @ W2^T. Same DMA/asm streaming loop.
// Steady wait vmcnt(10) = drain{stage(t)2, loadA(t)6}, keep 10 in flight.
// grid: (E=8, H/TN=64, 6), block 256.
// ---------------------------------------------------------------------------
__global__ __launch_bounds__(256, 2)
void gemm2_kernel(const unsigned short* __restrict__ act, const float* __restrict__ w2,
                  const float* __restrict__ s2, const int* __restrict__ offs,
                  float* __restrict__ buf)
{
  const int e   = blockIdx.x;
  const int off = offs[e];
  const int cnt = offs[e+1] - off;
  const int m0  = blockIdx.z * TM;
  if (m0 >= cnt) return;
  const int rows = min(TM, cnt - m0);
  const int nb   = blockIdx.y * TN;

  __shared__ __align__(16) float Bs[4][TN][BK];   // 4 x 8KB ring = 32 KB

  const int tid  = threadIdx.x;
  const int wv   = tid >> 6;
  const int lane = tid & 63;
  const int quad = lane >> 4;
  const int l16  = lane & 15;

  const float* w2e = w2 + (size_t)e * H_ * I_;
  const float* s2e = s2 + (size_t)e * (H_/128) * (I_/128);
  const int srow  = (nb >> 7) * (I_/128);

  // B staging: wave wv stages rows [wv*8, wv*8+8): 2 insts x 4 rows.
  const char* srcP[2];
  #pragma unroll
  for (int j = 0; j < 2; j++){
    const int rl = wv*8 + j*4 + (lane >> 4);
    const int cb = ((lane & 15) << 4) ^ ((rl & 7) << 4);
    srcP[j] = (const char*)(w2e + (size_t)(nb + rl) * I_) + cb;
  }
  auto stage = [&](int t, int slot){
    #pragma unroll
    for (int j = 0; j < 2; j++)
      gload_lds16(srcP[j] + (size_t)t * (BK*4), &Bs[slot][wv*8 + j*4][0]);
  };

  const unsigned short* aP[MT_];
  #pragma unroll
  for (int mt = 0; mt < MT_; mt++){
    int sl = off + m0 + wv*(TM/4) + mt*16 + l16;
    sl = min(sl, NPAIR - 1);
    aP[mt] = act + (size_t)sl * I_ + quad*8;
  }

  f32x4 acc[MT_][2];
  #pragma unroll
  for (int mt = 0; mt < MT_; mt++)
    #pragma unroll
    for (int nt = 0; nt < 2; nt++)
      acc[mt][nt] = (f32x4){0.f, 0.f, 0.f, 0.f};

  i32x4 A0[6], A1[6], A2[6], A3[6];
  auto loadA = [&](int t, i32x4* A){
    #pragma unroll
    for (int kk = 0; kk < 2; kk++)
      #pragma unroll
      for (int mt = 0; mt < MT_; mt++)
        A[kk*MT_ + mt] = gload16(aP[mt] + t*BK + kk*32);
  };

  auto comp = [&](int slot, const i32x4* A, float s){
    #pragma unroll
    for (int kk = 0; kk < 2; kk++)
      #pragma unroll
      for (int nt = 0; nt < 2; nt++){
        const int row = nt*16 + l16;
        const int xr  = (row & 7) << 2;
        const int cb  = kk*32 + quad*8;
        const float4 F0 = *(const float4*)&Bs[slot][row][cb ^ xr];
        const float4 F1 = *(const float4*)&Bs[slot][row][(cb + 4) ^ xr];
        u16x8 o; cvt4(o, 0, F0, s); cvt4(o, 4, F1, s);
        const bf16x8 bv = u2b(o);
        #pragma unroll
        for (int mt = 0; mt < MT_; mt++){
          const bf16x8 av = *(const bf16x8*)&A[kk*MT_ + mt];
          acc[mt][nt] = __builtin_amdgcn_mfma_f32_16x16x32_bf16(av, bv, acc[mt][nt], 0, 0, 0);
        }
      }
  };

  const int NITER = I_/BK;   // 44
  // prologue: loadA(0)6, stage(0)2, stage(1)2, loadA(1)6, stage(2)2 = 18 ops
  loadA(0, A0);
  stage(0, 0);
  stage(1, 1);
  loadA(1, A1);
  stage(2, 2);
  WAIT_BAR(10)                    // drain loadA(0)+stage(0)
  loadA(2, A2);
  stage(3, 3);
  comp(0, A0, s2e[srow]);

#define G2_STEP(T, AL, AC)                                        \
  { WAIT_BAR(10)                                                  \
    loadA((T)+2, AL);                                             \
    stage((T)+3, ((T)+3) & 3);                                    \
    comp((T) & 3, AC, s2e[srow + ((T) >> 1)]); }

  for (int tb = 1; tb <= 37; tb += 4){
    G2_STEP(tb+0, A3, A1)
    G2_STEP(tb+1, A0, A2)
    G2_STEP(tb+2, A1, A3)
    G2_STEP(tb+3, A2, A0)
  }
  // t = 41 (steady wait; loadA(43), no stage)
  { WAIT_BAR(10)
    loadA(43, A3);
    comp(1, A1, s2e[srow + 20]); }
  // t = 42: outstanding = stage(42)2, loadA(42)6, stage(43)2, loadA(43)6
  { WAIT_BAR(8)
    comp(2, A2, s2e[srow + 21]); }
  // t = 43
  { WAIT_BAR(0)
    comp(3, A3, s2e[srow + 21]); }
#undef G2_STEP

  // epilogue: plain stores per slot row
  #pragma unroll
  for (int mt = 0; mt < MT_; mt++){
    #pragma unroll
    for (int nt = 0; nt < 2; nt++){
      #pragma unroll
      for (int r = 0; r < 4; r++){
        const int m = wv*(TM/4) + mt*16 + quad*4 + r;
        if (m < rows)
          buf[(size_t)(off + m0 + m)*H_ + (nb + nt*16 + l16)] = acc[mt][nt][r];
      }
    }
  }
}

// ---------------------------------------------------------------------------
// Combine: out[t,:] = tw[2t]*buf[sop[2t],:] + tw[2t+1]*buf[sop[2t+1],:]
// ---------------------------------------------------------------------------
__global__ void combine_kernel(const float* __restrict__ buf, const int* __restrict__ sop,
                               const float* __restrict__ tw, float* __restrict__ out){
  const int gid = blockIdx.x*256 + threadIdx.x;
  const int t = gid >> 9;
  const int c = gid & 511;
  const int s0 = sop[2*t], s1 = sop[2*t+1];
  const float w0 = tw[2*t], w1 = tw[2*t+1];
  const float4 v0 = ((const float4*)buf)[(size_t)s0*(H_/4) + c];
  const float4 v1 = ((const float4*)buf)[(size_t)s1*(H_/4) + c];
  float4 o;
  o.x = w0*v0.x + w1*v1.x;
  o.y = w0*v0.y + w1*v1.y;
  o.z = w0*v0.z + w1*v1.z;
  o.w = w0*v0.w + w1*v1.w;
  ((float4*)out)[gid] = o;
}

// ---------------------------------------------------------------------------
extern "C" void kernel_launch(void* const* d_in, const int* in_sizes, int n_in,
                              void* d_out, int out_size, void* d_ws, size_t ws_size,
                              hipStream_t stream){
  const float* x   = (const float*)d_in[0];
  const int*   ids = (const int*)  d_in[1];
  const float* tw  = (const float*)d_in[2];
  const float* w13 = (const float*)d_in[3];
  const float* s13 = (const float*)d_in[4];
  const float* w2  = (const float*)d_in[5];
  const float* s2  = (const float*)d_in[6];
  float* out = (float*)d_out;

  char* ws = (char*)d_ws;
  int* offs = (int*)ws;                                   // 9 ints
  int* ptok = (int*)(ws + 64);                            // 1024 ints
  int* sop  = (int*)(ws + 64 + 4096);                     // 1024 ints
  unsigned short* xg  = (unsigned short*)(ws + 16384);    // [1024][H] bf16 (aliased by buf)
  float*          buf = (float*)(ws + 16384);             // [1024][H] f32
  unsigned short* act = (unsigned short*)(ws + 16384 + (size_t)NPAIR*H_*4);  // [1024][I] bf16

  route_kernel  <<<1, NPAIR, 0, stream>>>(ids, offs, ptok, sop);
  prep_kernel   <<<NPAIR, 256, 0, stream>>>(x, ptok, xg);
  gemm1_kernel  <<<dim3(E_, I_/TN, (NPAIR + TM - 1)/TM), 256, 0, stream>>>(xg, w13, s13, offs, act);
  gemm2_kernel  <<<dim3(E_, H_/TN, (NPAIR + TM - 1)/TM), 256, 0, stream>>>(act, w2, s2, offs, buf);
  combine_kernel<<<(T_*H_/4)/256, 256, 0, stream>>>(buf, sop, tw, out);
}